// Round 5
// baseline (128.376 us; speedup 1.0000x reference)
//
#include <hip/hip_runtime.h>

#define B_      2
#define C_      256
#define H_      96
#define W_      96
#define HW_     (H_ * W_)
#define P_      7
#define PP_     (P_ * P_)
#define NROIS_  512
#define SCALE_  0.0625f
#define TSTD_   0.1f

#define NGROUP_ 8                       // channel groups (one per XCD)
#define GC_     (C_ / NGROUP_)          // 32 channels per group

// s_getreg(HW_REG_XCC_ID): id=20, offset=0, size=4  ->  20 | (3<<11)
#define XCC_ID_IMM 6164

// f32 -> bf16 (round-to-nearest-even), as raw ushort bits
__device__ __forceinline__ unsigned f2bf(float f) {
    union { float f; unsigned u; } x; x.f = f;
    return (x.u + 0x7fffu + ((x.u >> 16) & 1u)) >> 16;
}
__device__ __forceinline__ float bf_lo(unsigned u) {
    union { unsigned i; float f; } x; x.i = u << 16; return x.f;
}
__device__ __forceinline__ float bf_hi(unsigned u) {
    union { unsigned i; float f; } x; x.i = u & 0xffff0000u; return x.f;
}

// ---------------------------------------------------------------------------
// Zero the per-group work-queue counters (ws is poisoned 0xAA every launch).
// ---------------------------------------------------------------------------
__global__ void zero_counters(int* __restrict__ c) {
    if (threadIdx.x < NGROUP_) c[threadIdx.x] = 0;
}

// ---------------------------------------------------------------------------
// Pass 1: f32 CHW -> bf16 group-planar [b][g][HW][32ch]. (unchanged from R4)
// ---------------------------------------------------------------------------
__global__ __launch_bounds__(256) void nchw_to_gp_bf16(const float* __restrict__ in,
                                                       ushort* __restrict__ out) {
    __shared__ float tile[32][33];          // [ch][px], +1 pad
    const int b   = blockIdx.z;
    const int g   = blockIdx.x & (NGROUP_ - 1);
    const int p0  = (blockIdx.x >> 3) * 32; // pixel tile origin
    const int c0  = g * 32;                 // channel tile origin
    const int tid = threadIdx.x;

    const float* src = in + (size_t)b * (C_ * HW_);
    ushort*      dst = out + ((size_t)(b * NGROUP_ + g) * HW_) * GC_;

    const int px = tid & 31, cr = tid >> 5;
#pragma unroll
    for (int k = 0; k < 32; k += 8)
        tile[cr + k][px] =
            __builtin_nontemporal_load(&src[(size_t)(c0 + cr + k) * HW_ + p0 + px]);
    __syncthreads();

    const int cp = tid & 15, py = tid >> 4;  // cp: ch-pair, py: pixel
    unsigned* dst32 = (unsigned*)dst;
#pragma unroll
    for (int k = 0; k < 32; k += 16) {
        const int p = py + k;
        const unsigned u0 = f2bf(tile[2 * cp + 0][p]);
        const unsigned u1 = f2bf(tile[2 * cp + 1][p]);
        dst32[(size_t)(p0 + p) * (GC_ / 2) + cp] = u0 | (u1 << 16);
    }
}

// ---------------------------------------------------------------------------
// Pass 2: XCC-pinned work queue. Each block reads its REAL XCC id and claims
// a (roi, group) item preferring group == xcc -> group g's 1.18 MB bf16 slice
// is only ever read by XCD g's L2 (true pinning, no dispatch-order
// assumption). Claim loop is guaranteed to terminate with exactly one item
// per block (counter >= 512 implies 512 successful claims on that group);
// even a bogus xcc read only costs locality, never correctness.
// 4 lanes/bin x uint4 (8 bf16 ch) = 64 B = one line per corner.
// ---------------------------------------------------------------------------
__global__ __launch_bounds__(256) void dpsroi_pool5(const ushort* __restrict__ feat, // bf16 gp
                                                    const float* __restrict__ rois,
                                                    const float* __restrict__ trans,
                                                    float* __restrict__ out,
                                                    int* __restrict__ qcnt) {
    __shared__ float sout[GC_ * PP_];       // 32*49*4 = 6272 B, global layout
    __shared__ int   s_item;

    const int tid = threadIdx.x;

    if (tid == 0) {
        const int xcc = __builtin_amdgcn_s_getreg(XCC_ID_IMM) & (NGROUP_ - 1);
        int item = -1;
#pragma unroll 1
        for (int t = 0; t < NGROUP_ && item < 0; ++t) {
            const int gg  = (xcc + t) & (NGROUP_ - 1);
            const int idx = atomicAdd(&qcnt[gg], 1);
            if (idx < NROIS_) item = (idx << 3) | gg;
        }
        s_item = item;
    }
    __syncthreads();
    const int item = s_item;
    if (item < 0) return;                   // unreachable (see proof); safety
    const int g = item & (NGROUP_ - 1);
    const int n = item >> 3;

    const int bin = tid >> 2;               // 0..63 (49 active)
    const int ch0 = (tid & 3) * 8;          // 8 channels per lane

    // ROI geometry (block-uniform)
    const int   broi = (int)rois[n * 5 + 0];
    const float x1 = rintf(rois[n * 5 + 1]) * SCALE_ - 0.5f;
    const float y1 = rintf(rois[n * 5 + 2]) * SCALE_ - 0.5f;
    const float x2 = (rintf(rois[n * 5 + 3]) + 1.0f) * SCALE_ - 0.5f;
    const float y2 = (rintf(rois[n * 5 + 4]) + 1.0f) * SCALE_ - 0.5f;
    const float rw = fmaxf(x2 - x1, 0.1f);
    const float rh = fmaxf(y2 - y1, 0.1f);
    const float bin_w = rw * (1.0f / 7.0f);
    const float bin_h = rh * (1.0f / 7.0f);
    const float sub_w = bin_w * 0.5f;
    const float sub_h = bin_h * 0.5f;

    const ushort* fb = feat + ((size_t)(broi * NGROUP_ + g) * HW_) * GC_ + ch0;

    if (bin < PP_) {
        const int pi = bin / P_;
        const int pj = bin - pi * P_;
        const float tx = trans[((n * 2 + 0) * P_ + pi) * P_ + pj] * TSTD_;
        const float ty = trans[((n * 2 + 1) * P_ + pi) * P_ + pj] * TSTD_;
        const float wstart = (float)pj * bin_w + x1 + tx * rw;
        const float hstart = (float)pi * bin_h + y1 + ty * rh;

        float wt[4][4];
        int   ofs[4][4];
        int   cnt = 0;
#pragma unroll
        for (int s = 0; s < 4; ++s) {
            const float w = wstart + (float)(s & 1) * sub_w;
            const float h = hstart + (float)(s >> 1) * sub_h;
            const bool valid = (w >= -0.5f) & (w <= (float)W_ - 0.5f) &
                               (h >= -0.5f) & (h <= (float)H_ - 0.5f);
            cnt += valid ? 1 : 0;
            const float vf = valid ? 1.0f : 0.0f;
            const float wc  = fminf(fmaxf(w, 0.0f), (float)(W_ - 1));
            const float hc  = fminf(fmaxf(h, 0.0f), (float)(H_ - 1));
            const float x0f = floorf(wc), y0f = floorf(hc);
            const float dx  = wc - x0f,   dy  = hc - y0f;
            const int   x0  = (int)x0f,   y0  = (int)y0f;
            const int   xp  = (int)ceilf(wc), yp = (int)ceilf(hc);
            wt[s][0] = vf * (1.0f - dx) * (1.0f - dy);
            wt[s][1] = vf * dx * (1.0f - dy);
            wt[s][2] = vf * (1.0f - dx) * dy;
            wt[s][3] = vf * dx * dy;
            ofs[s][0] = y0 * W_ + x0;
            ofs[s][1] = y0 * W_ + xp;
            ofs[s][2] = yp * W_ + x0;
            ofs[s][3] = yp * W_ + xp;
        }

        float acc[8] = {0.f, 0.f, 0.f, 0.f, 0.f, 0.f, 0.f, 0.f};
#pragma unroll
        for (int s = 0; s < 4; ++s) {
            uint4 v[4];
#pragma unroll
            for (int c = 0; c < 4; ++c)
                v[c] = *(const uint4*)(fb + (size_t)ofs[s][c] * GC_);
#pragma unroll
            for (int c = 0; c < 4; ++c) {
                const float wgt = wt[s][c];
                acc[0] += wgt * bf_lo(v[c].x);
                acc[1] += wgt * bf_hi(v[c].x);
                acc[2] += wgt * bf_lo(v[c].y);
                acc[3] += wgt * bf_hi(v[c].y);
                acc[4] += wgt * bf_lo(v[c].z);
                acc[5] += wgt * bf_hi(v[c].z);
                acc[6] += wgt * bf_lo(v[c].w);
                acc[7] += wgt * bf_hi(v[c].w);
            }
        }

        const float inv = (cnt > 0) ? (1.0f / (float)cnt) : 0.0f;
#pragma unroll
        for (int j = 0; j < 8; ++j)
            sout[(ch0 + j) * PP_ + bin] = acc[j] * inv;
    }

    __syncthreads();
    // out[n, g*32 : (g+1)*32, :, :] contiguous: 32*49 = 1568 floats
    float* outn = out + ((size_t)n * C_ + g * GC_) * PP_;
    for (int f = tid; f < GC_ * PP_; f += 256)
        __builtin_nontemporal_store(sout[f], &outn[f]);
}

extern "C" void kernel_launch(void* const* d_in, const int* in_sizes, int n_in,
                              void* d_out, int out_size, void* d_ws, size_t ws_size,
                              hipStream_t stream) {
    const float* feat  = (const float*)d_in[0];   // (2,256,96,96) f32
    const float* rois  = (const float*)d_in[1];   // (512,5)
    const float* trans = (const float*)d_in[2];   // (512,2,7,7)
    float* out = (float*)d_out;                   // (512,256,7,7) f32

    ushort* gp  = (ushort*)d_ws;                  // bf16 group-planar, 9.4 MB
    int*    qct = (int*)((char*)d_ws + (32u << 20)); // queue counters @ +32 MiB

    zero_counters<<<1, 64, 0, stream>>>(qct);
    dim3 tb(256);
    dim3 tg((HW_ / 32) * NGROUP_, 1, B_);         // g = blockIdx.x & 7
    nchw_to_gp_bf16<<<tg, tb, 0, stream>>>(feat, gp);
    dpsroi_pool5<<<NROIS_ * NGROUP_, 256, 0, stream>>>(gp, rois, trans, out, qct);
}

// Round 6
// 90.600 us; speedup vs baseline: 1.4170x; 1.4170x over previous
//
#include <hip/hip_runtime.h>

#define B_      2
#define C_      256
#define H_      96
#define W_      96
#define HW_     (H_ * W_)
#define P_      7
#define PP_     (P_ * P_)
#define NROIS_  512
#define SCALE_  0.0625f
#define TSTD_   0.1f

#define NGROUP_ 8                       // channel groups
#define GC_     (C_ / NGROUP_)          // 32 channels per group

// f32 -> bf16 (round-to-nearest-even), as raw ushort bits
__device__ __forceinline__ unsigned f2bf(float f) {
    union { float f; unsigned u; } x; x.f = f;
    return (x.u + 0x7fffu + ((x.u >> 16) & 1u)) >> 16;
}
__device__ __forceinline__ float bf_lo(unsigned u) {
    union { unsigned i; float f; } x; x.i = u << 16; return x.f;
}
__device__ __forceinline__ float bf_hi(unsigned u) {
    union { unsigned i; float f; } x; x.i = u & 0xffff0000u; return x.f;
}

// ---------------------------------------------------------------------------
// Pass 1: f32 CHW -> bf16 group-planar [b][g][HW][32ch]. (R4, unchanged)
// nt-loads on the once-read CHW source; plain stores on gp (pool's input).
// ---------------------------------------------------------------------------
__global__ __launch_bounds__(256) void nchw_to_gp_bf16(const float* __restrict__ in,
                                                       ushort* __restrict__ out) {
    __shared__ float tile[32][33];          // [ch][px], +1 pad
    const int b   = blockIdx.z;
    const int g   = blockIdx.x & (NGROUP_ - 1);
    const int p0  = (blockIdx.x >> 3) * 32; // pixel tile origin
    const int c0  = g * 32;                 // channel tile origin
    const int tid = threadIdx.x;

    const float* src = in + (size_t)b * (C_ * HW_);
    ushort*      dst = out + ((size_t)(b * NGROUP_ + g) * HW_) * GC_;

    const int px = tid & 31, cr = tid >> 5;
#pragma unroll
    for (int k = 0; k < 32; k += 8)
        tile[cr + k][px] =
            __builtin_nontemporal_load(&src[(size_t)(c0 + cr + k) * HW_ + p0 + px]);
    __syncthreads();

    const int cp = tid & 15, py = tid >> 4;  // cp: ch-pair, py: pixel
    unsigned* dst32 = (unsigned*)dst;
#pragma unroll
    for (int k = 0; k < 32; k += 16) {
        const int p = py + k;
        const unsigned u0 = f2bf(tile[2 * cp + 0][p]);
        const unsigned u1 = f2bf(tile[2 * cp + 1][p]);
        dst32[(size_t)(p0 + p) * (GC_ / 2) + cp] = u0 | (u1 << 16);
    }
}

// ---------------------------------------------------------------------------
// Pass 2: block = (roi n, group g), g = blockIdx.x & 7 (static; R5's atomic
// queue serialized block starts and regressed -- reverted).
// R5 counters: FETCH 4.9 MB, HBM 7%, VALU 22% -> latency-bound, and
// VGPR_Count=52 proves MLP was ~4 loads in flight.  This version computes
// ALL 16 offsets/weights first, issues ALL 16 uint4 gathers into an explicit
// register array (forces ~64 data VGPRs -> MLP=16/wave), then unpacks/FMAs
// in load order so vmcnt waits pipeline.
// ---------------------------------------------------------------------------
__global__ __launch_bounds__(256) void dpsroi_pool6(const ushort* __restrict__ feat, // bf16 gp
                                                    const float* __restrict__ rois,
                                                    const float* __restrict__ trans,
                                                    float* __restrict__ out) {
    __shared__ float sout[GC_ * PP_];       // 32*49*4 = 6272 B, global layout

    const int blk = blockIdx.x;
    const int g   = blk & (NGROUP_ - 1);
    const int n   = blk >> 3;
    const int tid = threadIdx.x;
    const int bin = tid >> 2;               // 0..63 (49 active)
    const int ch0 = (tid & 3) * 8;          // 8 channels per lane

    // ROI geometry (block-uniform)
    const int   broi = (int)rois[n * 5 + 0];
    const float x1 = rintf(rois[n * 5 + 1]) * SCALE_ - 0.5f;
    const float y1 = rintf(rois[n * 5 + 2]) * SCALE_ - 0.5f;
    const float x2 = (rintf(rois[n * 5 + 3]) + 1.0f) * SCALE_ - 0.5f;
    const float y2 = (rintf(rois[n * 5 + 4]) + 1.0f) * SCALE_ - 0.5f;
    const float rw = fmaxf(x2 - x1, 0.1f);
    const float rh = fmaxf(y2 - y1, 0.1f);
    const float bin_w = rw * (1.0f / 7.0f);
    const float bin_h = rh * (1.0f / 7.0f);
    const float sub_w = bin_w * 0.5f;
    const float sub_h = bin_h * 0.5f;

    const ushort* fb = feat + ((size_t)(broi * NGROUP_ + g) * HW_) * GC_ + ch0;

    if (bin < PP_) {
        const int pi = bin / P_;
        const int pj = bin - pi * P_;
        const float tx = trans[((n * 2 + 0) * P_ + pi) * P_ + pj] * TSTD_;
        const float ty = trans[((n * 2 + 1) * P_ + pi) * P_ + pj] * TSTD_;
        const float wstart = (float)pj * bin_w + x1 + tx * rw;
        const float hstart = (float)pi * bin_h + y1 + ty * rh;

        // ---- phase 1: all 16 weights + offsets ----
        float wt[16];
        int   ofs[16];
        int   cnt = 0;
#pragma unroll
        for (int s = 0; s < 4; ++s) {
            const float w = wstart + (float)(s & 1) * sub_w;
            const float h = hstart + (float)(s >> 1) * sub_h;
            const bool valid = (w >= -0.5f) & (w <= (float)W_ - 0.5f) &
                               (h >= -0.5f) & (h <= (float)H_ - 0.5f);
            cnt += valid ? 1 : 0;
            const float vf = valid ? 1.0f : 0.0f;
            const float wc  = fminf(fmaxf(w, 0.0f), (float)(W_ - 1));
            const float hc  = fminf(fmaxf(h, 0.0f), (float)(H_ - 1));
            const float x0f = floorf(wc), y0f = floorf(hc);
            const float dx  = wc - x0f,   dy  = hc - y0f;
            const int   x0  = (int)x0f,   y0  = (int)y0f;
            const int   xp  = (int)ceilf(wc), yp = (int)ceilf(hc);
            wt[4 * s + 0] = vf * (1.0f - dx) * (1.0f - dy);
            wt[4 * s + 1] = vf * dx * (1.0f - dy);
            wt[4 * s + 2] = vf * (1.0f - dx) * dy;
            wt[4 * s + 3] = vf * dx * dy;
            ofs[4 * s + 0] = y0 * W_ + x0;
            ofs[4 * s + 1] = y0 * W_ + xp;
            ofs[4 * s + 2] = yp * W_ + x0;
            ofs[4 * s + 3] = yp * W_ + xp;
        }

        // ---- phase 2: ALL 16 gathers in flight ----
        uint4 v[16];
#pragma unroll
        for (int i = 0; i < 16; ++i)
            v[i] = *(const uint4*)(fb + (size_t)ofs[i] * GC_);

        // ---- phase 3: unpack + FMA in load order (pipelined vmcnt waits) --
        float acc[8] = {0.f, 0.f, 0.f, 0.f, 0.f, 0.f, 0.f, 0.f};
#pragma unroll
        for (int i = 0; i < 16; ++i) {
            const float wgt = wt[i];
            acc[0] += wgt * bf_lo(v[i].x);
            acc[1] += wgt * bf_hi(v[i].x);
            acc[2] += wgt * bf_lo(v[i].y);
            acc[3] += wgt * bf_hi(v[i].y);
            acc[4] += wgt * bf_lo(v[i].z);
            acc[5] += wgt * bf_hi(v[i].z);
            acc[6] += wgt * bf_lo(v[i].w);
            acc[7] += wgt * bf_hi(v[i].w);
        }

        const float inv = (cnt > 0) ? (1.0f / (float)cnt) : 0.0f;
#pragma unroll
        for (int j = 0; j < 8; ++j)
            sout[(ch0 + j) * PP_ + bin] = acc[j] * inv;
    }

    __syncthreads();
    // out[n, g*32 : (g+1)*32, :, :] contiguous: 32*49 = 1568 floats
    float* outn = out + ((size_t)n * C_ + g * GC_) * PP_;
    for (int f = tid; f < GC_ * PP_; f += 256)
        __builtin_nontemporal_store(sout[f], &outn[f]);
}

extern "C" void kernel_launch(void* const* d_in, const int* in_sizes, int n_in,
                              void* d_out, int out_size, void* d_ws, size_t ws_size,
                              hipStream_t stream) {
    const float* feat  = (const float*)d_in[0];   // (2,256,96,96) f32
    const float* rois  = (const float*)d_in[1];   // (512,5)
    const float* trans = (const float*)d_in[2];   // (512,2,7,7)
    float* out = (float*)d_out;                   // (512,256,7,7) f32

    ushort* gp = (ushort*)d_ws;                   // bf16 group-planar, 9.4 MB
    dim3 tb(256);
    dim3 tg((HW_ / 32) * NGROUP_, 1, B_);         // g = blockIdx.x & 7
    nchw_to_gp_bf16<<<tg, tb, 0, stream>>>(feat, gp);
    dpsroi_pool6<<<NROIS_ * NGROUP_, 256, 0, stream>>>(gp, rois, trans, out);
}

// Round 8
// 90.294 us; speedup vs baseline: 1.4217x; 1.0034x over previous
//
#include <hip/hip_runtime.h>

#define B_      2
#define C_      256
#define H_      96
#define W_      96
#define HW_     (H_ * W_)
#define P_      7
#define PP_     (P_ * P_)
#define NROIS_  512
#define SCALE_  0.0625f
#define TSTD_   0.1f

#define NGROUP_ 8                       // channel groups
#define GC_     (C_ / NGROUP_)          // 32 channels per group

typedef float vf4 __attribute__((ext_vector_type(4)));   // native vec for nt builtins

// f32 -> bf16 (round-to-nearest-even), as raw bits
__device__ __forceinline__ unsigned f2bf(float f) {
    union { float f; unsigned u; } x; x.f = f;
    return (x.u + 0x7fffu + ((x.u >> 16) & 1u)) >> 16;
}
__device__ __forceinline__ float bf_lo(unsigned u) {
    union { unsigned i; float f; } x; x.i = u << 16; return x.f;
}
__device__ __forceinline__ float bf_hi(unsigned u) {
    union { unsigned i; float f; } x; x.i = u & 0xffff0000u; return x.f;
}

// ---------------------------------------------------------------------------
// Pass 1: f32 CHW -> bf16 group-planar [b][g][HW][32ch].
// Read: ONE vf4 pass (32ch x 32px per block, 128 B segments / 8 lanes).
// Tile row stride 36 floats -> 16B-aligned vector LDS writes.
// Write: one pass, uint2 (4 packed bf16) per lane, coalesced.
// ---------------------------------------------------------------------------
__global__ __launch_bounds__(256) void nchw_to_gp_bf16(const float* __restrict__ in,
                                                       ushort* __restrict__ out) {
    __shared__ float tile[32][36];          // [ch][px], stride 36: b128-aligned
    const int b   = blockIdx.z;
    const int g   = blockIdx.x & (NGROUP_ - 1);
    const int p0  = (blockIdx.x >> 3) * 32; // pixel tile origin
    const int c0  = g * 32;                 // channel tile origin
    const int tid = threadIdx.x;

    const float* src = in + (size_t)b * (C_ * HW_);
    ushort*      dst = out + ((size_t)(b * NGROUP_ + g) * HW_) * GC_;

    // read: lane = (ch row, px quad); one vf4 per thread covers 32x32
    {
        const int cr = tid >> 3;            // 0..31 channel row
        const int pq = (tid & 7) * 4;       // pixel quad
        const vf4 v = __builtin_nontemporal_load(
            (const vf4*)&src[(size_t)(c0 + cr) * HW_ + p0 + pq]);
        *(vf4*)&tile[cr][pq] = v;
    }
    __syncthreads();

    // write: lane = (px, ch quad); pack 4 ch -> uint2, coalesced
    {
        const int p  = tid >> 3;            // 0..31 pixel
        const int cq = (tid & 7) * 4;       // channel quad
        uint2 o;
        o.x = f2bf(tile[cq + 0][p]) | (f2bf(tile[cq + 1][p]) << 16);
        o.y = f2bf(tile[cq + 2][p]) | (f2bf(tile[cq + 3][p]) << 16);
        *(uint2*)&((unsigned*)dst)[(size_t)(p0 + p) * (GC_ / 2) + (cq >> 1)] = o;
    }
}

// ---------------------------------------------------------------------------
// Pass 2: block = (roi n, group g), g = blockIdx.x & 7 (static XCD affinity).
// 4 lanes/bin x uint4 (8 bf16 ch) = 64 B line per corner; all 16 gathers
// hoisted in flight.  __launch_bounds__(256,4): pin >=4 waves/SIMD — the
// v[16]+wt+ofs register set sits right at the 128-VGPR occupancy cliff and
// a creep past it would halve outstanding lines (the suspected R6 limiter).
// ---------------------------------------------------------------------------
__global__ __launch_bounds__(256, 4) void dpsroi_pool7(const ushort* __restrict__ feat,
                                                       const float* __restrict__ rois,
                                                       const float* __restrict__ trans,
                                                       float* __restrict__ out) {
    __shared__ float sout[GC_ * PP_];       // 32*49*4 = 6272 B, global layout

    const int blk = blockIdx.x;
    const int g   = blk & (NGROUP_ - 1);
    const int n   = blk >> 3;
    const int tid = threadIdx.x;
    const int bin = tid >> 2;               // 0..63 (49 active)
    const int ch0 = (tid & 3) * 8;          // 8 channels per lane

    // ROI geometry (block-uniform)
    const int   broi = (int)rois[n * 5 + 0];
    const float x1 = rintf(rois[n * 5 + 1]) * SCALE_ - 0.5f;
    const float y1 = rintf(rois[n * 5 + 2]) * SCALE_ - 0.5f;
    const float x2 = (rintf(rois[n * 5 + 3]) + 1.0f) * SCALE_ - 0.5f;
    const float y2 = (rintf(rois[n * 5 + 4]) + 1.0f) * SCALE_ - 0.5f;
    const float rw = fmaxf(x2 - x1, 0.1f);
    const float rh = fmaxf(y2 - y1, 0.1f);
    const float bin_w = rw * (1.0f / 7.0f);
    const float bin_h = rh * (1.0f / 7.0f);
    const float sub_w = bin_w * 0.5f;
    const float sub_h = bin_h * 0.5f;

    const ushort* fb = feat + ((size_t)(broi * NGROUP_ + g) * HW_) * GC_ + ch0;

    if (bin < PP_) {
        const int pi = bin / P_;
        const int pj = bin - pi * P_;
        const float tx = trans[((n * 2 + 0) * P_ + pi) * P_ + pj] * TSTD_;
        const float ty = trans[((n * 2 + 1) * P_ + pi) * P_ + pj] * TSTD_;
        const float wstart = (float)pj * bin_w + x1 + tx * rw;
        const float hstart = (float)pi * bin_h + y1 + ty * rh;

        // ---- phase 1: all 16 weights + offsets ----
        float wt[16];
        int   ofs[16];
        int   cnt = 0;
#pragma unroll
        for (int s = 0; s < 4; ++s) {
            const float w = wstart + (float)(s & 1) * sub_w;
            const float h = hstart + (float)(s >> 1) * sub_h;
            const bool valid = (w >= -0.5f) & (w <= (float)W_ - 0.5f) &
                               (h >= -0.5f) & (h <= (float)H_ - 0.5f);
            cnt += valid ? 1 : 0;
            const float vf = valid ? 1.0f : 0.0f;
            const float wc  = fminf(fmaxf(w, 0.0f), (float)(W_ - 1));
            const float hc  = fminf(fmaxf(h, 0.0f), (float)(H_ - 1));
            const float x0f = floorf(wc), y0f = floorf(hc);
            const float dx  = wc - x0f,   dy  = hc - y0f;
            const int   x0  = (int)x0f,   y0  = (int)y0f;
            const int   xp  = (int)ceilf(wc), yp = (int)ceilf(hc);
            wt[4 * s + 0] = vf * (1.0f - dx) * (1.0f - dy);
            wt[4 * s + 1] = vf * dx * (1.0f - dy);
            wt[4 * s + 2] = vf * (1.0f - dx) * dy;
            wt[4 * s + 3] = vf * dx * dy;
            ofs[4 * s + 0] = y0 * W_ + x0;
            ofs[4 * s + 1] = y0 * W_ + xp;
            ofs[4 * s + 2] = yp * W_ + x0;
            ofs[4 * s + 3] = yp * W_ + xp;
        }

        // ---- phase 2: ALL 16 gathers in flight ----
        uint4 v[16];
#pragma unroll
        for (int i = 0; i < 16; ++i)
            v[i] = *(const uint4*)(fb + (size_t)ofs[i] * GC_);

        // ---- phase 3: unpack + FMA in load order ----
        float acc[8] = {0.f, 0.f, 0.f, 0.f, 0.f, 0.f, 0.f, 0.f};
#pragma unroll
        for (int i = 0; i < 16; ++i) {
            const float wgt = wt[i];
            acc[0] += wgt * bf_lo(v[i].x);
            acc[1] += wgt * bf_hi(v[i].x);
            acc[2] += wgt * bf_lo(v[i].y);
            acc[3] += wgt * bf_hi(v[i].y);
            acc[4] += wgt * bf_lo(v[i].z);
            acc[5] += wgt * bf_hi(v[i].z);
            acc[6] += wgt * bf_lo(v[i].w);
            acc[7] += wgt * bf_hi(v[i].w);
        }

        const float inv = (cnt > 0) ? (1.0f / (float)cnt) : 0.0f;
#pragma unroll
        for (int j = 0; j < 8; ++j)
            sout[(ch0 + j) * PP_ + bin] = acc[j] * inv;
    }

    __syncthreads();
    // out[n, g*32 : (g+1)*32, :, :] contiguous: 32*49 = 1568 floats
    float* outn = out + ((size_t)n * C_ + g * GC_) * PP_;
    for (int f = tid; f < GC_ * PP_; f += 256)
        __builtin_nontemporal_store(sout[f], &outn[f]);
}

extern "C" void kernel_launch(void* const* d_in, const int* in_sizes, int n_in,
                              void* d_out, int out_size, void* d_ws, size_t ws_size,
                              hipStream_t stream) {
    const float* feat  = (const float*)d_in[0];   // (2,256,96,96) f32
    const float* rois  = (const float*)d_in[1];   // (512,5)
    const float* trans = (const float*)d_in[2];   // (512,2,7,7)
    float* out = (float*)d_out;                   // (512,256,7,7) f32

    ushort* gp = (ushort*)d_ws;                   // bf16 group-planar, 9.4 MB
    dim3 tb(256);
    dim3 tg((HW_ / 32) * NGROUP_, 1, B_);         // g = blockIdx.x & 7
    nchw_to_gp_bf16<<<tg, tb, 0, stream>>>(feat, gp);
    dpsroi_pool7<<<NROIS_ * NGROUP_, 256, 0, stream>>>(gp, rois, trans, out);
}